// Round 6
// baseline (199.663 us; speedup 1.0000x reference)
//
#include <hip/hip_runtime.h>
#include <hip/hip_bf16.h>
#include <stdint.h>

#define NSEQ   2048
#define DMODEL 1024
#define NH     16
#define DH     64
#define BATCH  2
#define BH     (BATCH*NH)           // 32
#define MROWS  (BATCH*NSEQ)         // 4096

typedef unsigned short u16;
typedef __attribute__((ext_vector_type(8))) short s16x8;
typedef __attribute__((ext_vector_type(4))) float f32x4;

__device__ __forceinline__ void load16_to_lds(const void* g, void* l) {
    __builtin_amdgcn_global_load_lds(
        (const __attribute__((address_space(1))) void*)g,
        (__attribute__((address_space(3))) void*)l,
        16, 0, 0);
}

__device__ __forceinline__ float bf2f(u16 u) {
    union { uint32_t i; float f; } x; x.i = ((uint32_t)u) << 16; return x.f;
}
__device__ __forceinline__ u16 f2bf(float f) {
    union { float f; uint32_t i; } x; x.f = f;
    uint32_t r = x.i + 0x7FFFu + ((x.i >> 16) & 1u);  // RNE
    return (u16)(r >> 16);
}
// pack two fp32 -> bf16 pair (lo in low16, hi in high16)
__device__ __forceinline__ uint32_t pk2(float lo, float hi) {
    union { float f; uint32_t i; } a, b; a.f = lo; b.f = hi;
    return __builtin_amdgcn_perm(b.i + 0x7FFFu, a.i + 0x7FFFu, 0x07060302u);
}
// single-instruction pack (HW RNE): dst.lo16 = bf16(lo), dst.hi16 = bf16(hi)
__device__ __forceinline__ uint32_t cvtpk(float lo, float hi) {
    uint32_t r;
    asm("v_cvt_pk_bf16_f32 %0, %1, %2" : "=v"(r) : "v"(lo), "v"(hi));
    return r;
}

// ---------------------------------------------------------------------------
// fp32 -> bf16 conversion. grid (512,1,8): z<4 -> quarter-slices of x (4M),
// z=4..7 -> wq/wk/wv/wo (1M each).  Packs via v_cvt_pk_bf16_f32 (HW RNE).
// ---------------------------------------------------------------------------
__global__ void cvt_kernel(
    const float* __restrict__ x,
    const float* __restrict__ wq, const float* __restrict__ wk,
    const float* __restrict__ wv, const float* __restrict__ wo,
    u16* __restrict__ xb,
    u16* __restrict__ wqb, u16* __restrict__ wkb,
    u16* __restrict__ wvb, u16* __restrict__ wob)
{
    int z = blockIdx.z;
    const float* s = (z < 4) ? x  : (z == 4 ? wq  : z == 5 ? wk  : z == 6 ? wv  : wo);
    u16*         d = (z < 4) ? xb : (z == 4 ? wqb : z == 5 ? wkb : z == 6 ? wvb : wob);
    size_t off = (z < 4) ? ((size_t)z << 20) : 0;
    size_t i = off + (size_t)blockIdx.x * 2048 + (size_t)threadIdx.x * 8;
    float4 a = *(const float4*)(s + i);
    float4 b = *(const float4*)(s + i + 4);
    uint4 st;
    st.x = cvtpk(a.x, a.y);
    st.y = cvtpk(a.z, a.w);
    st.z = cvtpk(b.x, b.y);
    st.w = cvtpk(b.z, b.w);
    *(uint4*)(d + i) = st;
}

// ---------------------------------------------------------------------------
// QKV GEMM: C = A @ W^T. 128x128 tile, BK=64, 256 threads, 2 blocks/CU.
// XOR chunk swizzle: chunk c of row r stored at c ^ (r&7).
// z<2 : bf16 scatter -> [B,H,N,DH], rows PRE-SCALED by R = 2/(1-||v||^2)
//       + P factor table (float).
// z==2: bf16 transposed scatter -> [B,H,DH,N]  (V -> Vt, fused)
// ---------------------------------------------------------------------------
__global__ __launch_bounds__(256, 2) void gemm_bt(
    const u16* __restrict__ A,
    const u16* __restrict__ W0, const u16* __restrict__ W1, const u16* __restrict__ W2,
    void* __restrict__ C0, void* __restrict__ C1, void* __restrict__ C2,
    float* __restrict__ qtab, float* __restrict__ ktab)
{
    __shared__ __align__(16) char smem[32768];
    char* ldsA = smem;            // 16KB: 128 rows x 8 chunks x 16B
    char* ldsW = smem + 16384;

    const u16* W = (blockIdx.z == 0) ? W0 : (blockIdx.z == 1 ? W1 : W2);
    void*      C = (blockIdx.z == 0) ? C0 : (blockIdx.z == 1 ? C1 : C2);

    const int tid  = threadIdx.x;
    const int lane = tid & 63;
    const int w    = tid >> 6;
    const int quad = lane >> 4;
    const int l15  = lane & 15;
    const int m0   = blockIdx.y * 128;
    const int n0   = blockIdx.x * 128;
    const int wr   = (w >> 1) * 64;
    const int wc   = (w & 1) * 64;

    f32x4 acc[4][4];
    const f32x4 fz = {0.f, 0.f, 0.f, 0.f};
    #pragma unroll
    for (int i = 0; i < 4; i++)
        #pragma unroll
        for (int j = 0; j < 4; j++) acc[i][j] = fz;

    for (int k0 = 0; k0 < DMODEL; k0 += 64) {
        __syncthreads();
        #pragma unroll
        for (int i = 0; i < 4; i++) {
            int linear = tid + i * 256;          // 0..1023
            int row = linear >> 3;
            int sc  = linear & 7;
            int gc  = sc ^ (row & 7);
            load16_to_lds(A + (size_t)(m0 + row) * DMODEL + k0 + gc * 8, ldsA + linear * 16);
            load16_to_lds(W + (size_t)(n0 + row) * DMODEL + k0 + gc * 8, ldsW + linear * 16);
        }
        __syncthreads();
        #pragma unroll
        for (int ks = 0; ks < 2; ks++) {
            s16x8 af[4], bf[4];
            #pragma unroll
            for (int mi = 0; mi < 4; mi++) {
                int row = wr + mi * 16 + l15;
                int ch  = (ks * 4 + quad) ^ (row & 7);
                af[mi] = *(const s16x8*)(ldsA + row * 128 + ch * 16);
            }
            #pragma unroll
            for (int ni = 0; ni < 4; ni++) {
                int row = wc + ni * 16 + l15;
                int ch  = (ks * 4 + quad) ^ (row & 7);
                bf[ni] = *(const s16x8*)(ldsW + row * 128 + ch * 16);
            }
            #pragma unroll
            for (int mi = 0; mi < 4; mi++)
                #pragma unroll
                for (int ni = 0; ni < 4; ni++)
                    acc[mi][ni] = __builtin_amdgcn_mfma_f32_16x16x32_bf16(
                        af[mi], bf[ni], acc[mi][ni], 0, 0, 0);
        }
    }

    if (blockIdx.z < 2) {
        // Q / K: row-norm first, then store rows pre-scaled by R; table = P.
        float* tab = (blockIdx.z == 0) ? qtab : ktab;
        int h = (n0 + wc) >> 6;      // wave's 64-col span = one head
        #pragma unroll
        for (int mi = 0; mi < 4; mi++)
            #pragma unroll
            for (int r = 0; r < 4; r++) {
                int m = m0 + wr + mi * 16 + quad * 4 + r;
                int b = m >> 11, n = m & (NSEQ - 1);
                float ss = 0.f;
                #pragma unroll
                for (int ni = 0; ni < 4; ni++) {
                    float v = acc[mi][ni][r];
                    ss = fmaf(v, v, ss);
                }
                // butterfly over the 16-lane group -> full ||row||^2 in all
                ss += __shfl_xor(ss, 1);
                ss += __shfl_xor(ss, 2);
                ss += __shfl_xor(ss, 4);
                ss += __shfl_xor(ss, 8);
                float rr = 1.0f / (1.0f - ss);
                float Rr = 2.0f * rr;
                #pragma unroll
                for (int ni = 0; ni < 4; ni++) {
                    int o = n0 + wc + ni * 16 + l15;
                    int d = o & 63;
                    ((u16*)C)[(((size_t)(b * NH + h)) * NSEQ + n) * DH + d] =
                        f2bf(acc[mi][ni][r] * Rr);
                }
                if (l15 == 0)
                    tab[(size_t)(b * NH + h) * NSEQ + n] = (1.0f + ss) * rr;
            }
    } else {
        // V transposed: r=0..3 are consecutive n -> packed 8B stores
        #pragma unroll
        for (int mi = 0; mi < 4; mi++) {
            int mrow = m0 + wr + mi * 16 + quad * 4;
            int b = mrow >> 11, n = mrow & (NSEQ - 1);
            #pragma unroll
            for (int ni = 0; ni < 4; ni++) {
                int o = n0 + wc + ni * 16 + l15;
                int h = o >> 6, d = o & 63;
                uint2 st;
                st.x = pk2(acc[mi][ni][0], acc[mi][ni][1]);
                st.y = pk2(acc[mi][ni][2], acc[mi][ni][3]);
                *(uint2*)((u16*)C + (((size_t)(b * NH + h)) * DH + d) * NSEQ + n) = st;
            }
        }
    }
}

// ---------------------------------------------------------------------------
// Output-projection GEMM: C(fp32) = A @ W^T with 64(M)x128(N) tiles.
// 512 blocks -> 2 blocks/CU.  256 threads; wave = 32 rows x 64 cols.
// Double-buffered staging (r5).  LDS 48KB.
// ---------------------------------------------------------------------------
__global__ __launch_bounds__(256, 2) void gemm_m64(
    const u16* __restrict__ A, const u16* __restrict__ W, float* __restrict__ C)
{
    __shared__ __align__(16) char smem[49152];
    char* A0 = smem;
    char* W0p = smem + 8192;
    char* A1 = smem + 24576;
    char* W1p = smem + 32768;

    const int tid  = threadIdx.x;
    const int lane = tid & 63;
    const int w    = tid >> 6;
    const int quad = lane >> 4;
    const int l15  = lane & 15;
    const int m0   = blockIdx.y * 64;
    const int n0   = blockIdx.x * 128;
    const int wr   = (w >> 1) * 32;
    const int wc   = (w & 1) * 64;

    f32x4 acc[2][4];
    const f32x4 fz = {0.f, 0.f, 0.f, 0.f};
    #pragma unroll
    for (int i = 0; i < 2; i++)
        #pragma unroll
        for (int j = 0; j < 4; j++) acc[i][j] = fz;

    auto stage = [&](int k0, char* lA, char* lW) {
        #pragma unroll
        for (int i = 0; i < 2; i++) {           // A: 512 chunks
            int linear = tid + i * 256;
            int row = linear >> 3, sc = linear & 7, gc = sc ^ (row & 7);
            load16_to_lds(A + (size_t)(m0 + row) * DMODEL + k0 + gc * 8,
                          lA + linear * 16);
        }
        #pragma unroll
        for (int i = 0; i < 4; i++) {           // W: 1024 chunks
            int linear = tid + i * 256;
            int row = linear >> 3, sc = linear & 7, gc = sc ^ (row & 7);
            load16_to_lds(W + (size_t)(n0 + row) * DMODEL + k0 + gc * 8,
                          lW + linear * 16);
        }
    };

    auto compute = [&](const char* lA, const char* lW) {
        #pragma unroll
        for (int ks = 0; ks < 2; ks++) {
            s16x8 af[2], bf[4];
            #pragma unroll
            for (int mi = 0; mi < 2; mi++) {
                int row = wr + mi * 16 + l15;
                int ch  = (ks * 4 + quad) ^ (row & 7);
                af[mi] = *(const s16x8*)(lA + row * 128 + ch * 16);
            }
            #pragma unroll
            for (int ni = 0; ni < 4; ni++) {
                int row = wc + ni * 16 + l15;
                int ch  = (ks * 4 + quad) ^ (row & 7);
                bf[ni] = *(const s16x8*)(lW + row * 128 + ch * 16);
            }
            #pragma unroll
            for (int mi = 0; mi < 2; mi++)
                #pragma unroll
                for (int ni = 0; ni < 4; ni++)
                    acc[mi][ni] = __builtin_amdgcn_mfma_f32_16x16x32_bf16(
                        af[mi], bf[ni], acc[mi][ni], 0, 0, 0);
        }
    };

    stage(0, A0, W0p);
    __syncthreads();
    for (int k0 = 0; k0 < DMODEL; k0 += 128) {
        stage(k0 + 64, A1, W1p);
        compute(A0, W0p);
        __syncthreads();
        if (k0 + 128 < DMODEL)
            stage(k0 + 128, A0, W0p);
        compute(A1, W1p);
        __syncthreads();
    }

    #pragma unroll
    for (int mi = 0; mi < 2; mi++)
        #pragma unroll
        for (int r = 0; r < 4; r++) {
            int m = m0 + wr + mi * 16 + quad * 4 + r;
            #pragma unroll
            for (int ni = 0; ni < 4; ni++) {
                int o = n0 + wc + ni * 16 + l15;
                C[(size_t)m * DMODEL + o] = acc[mi][ni][r];
            }
        }
}

// ---------------------------------------------------------------------------
// Attention v7: 1024 threads = 4 q-waves x 4 j-groups (in-block S=4 kv-split),
// 32-j DOUBLE-BUFFERED tiles.  LDS = 4 grp x 2 buf x (4K K + 4K V) = 64KB ->
// 2 blocks/CU.  Per-wave state identical to r5 (64 VGPR = exactly the
// 8-waves/EU boundary) -> 32 waves/CU (was 16, grid-capped since r0).
// launch_bounds(1024,4): VGPR cap 128 -- NOT 8 (r1's cap-64 spill disaster).
// Same staging bytes, same reuse (4 q-waves/tile), same barriers/wave (17),
// dbuf retained (r4: +11%).  Epilogue: r2's proven 2-pass 4-way combine.
// Q,K arrive pre-scaled by R (r5); transform z = fmaf(Pq,Pk,-s2).
// Failure signatures: VGPR 65..128 -> occupancy stays ~35%, dur ~= r5 (ok);
// VGPR <=48 + FETCH >> 100MB -> spill (revert).
// ---------------------------------------------------------------------------
__global__ __launch_bounds__(1024, 4) void attn_kernel(
    const u16* __restrict__ Q,      // [BH][NSEQ][DH]  (pre-scaled by Rq)
    const u16* __restrict__ K,      // [BH][NSEQ][DH]  (pre-scaled by Rk)
    const u16* __restrict__ Vt,     // [BH][DH][NSEQ]
    const float* __restrict__ qtab, // P_q per row
    const float* __restrict__ ktab, // P_k per row
    u16* __restrict__ Attw)         // [B][NSEQ][DMODEL] bf16
{
    __shared__ __align__(16) char smem[65536];

    const int tid  = threadIdx.x;
    const int lane = tid & 63;
    const int w    = tid >> 6;       // 0..15
    const int g    = w >> 2;         // j-quarter group 0..3
    const int wq_  = w & 3;          // q-wave within group
    const int quad = lane >> 4;
    const int l15  = lane & 15;
    const int bh   = blockIdx.y;
    const int i0   = blockIdx.x * 128;
    const int qbase = i0 + wq_ * 32;
    const int gt   = tid & 255;      // tid within group (256 threads)

    // per-group 32-j tiles, double-buffered:
    // [0,16K): K buf0 (4KB/grp)  [16K,32K): V buf0  [32K,48K): K buf1  [48K,64K): V buf1
    char* bK0 = smem + g * 4096;             // 32 j-rows x 128B, swz8
    char* bV0 = smem + 16384 + g * 4096;     // 64 d-rows x 64B (32 j), swz (d>>1)&3
    char* bK1 = bK0 + 32768;
    char* bV1 = bV0 + 32768;

    // Q fragments (B-operand layout) -- already R-scaled at the source
    s16x8 qf[2][2];                 // [qt][ks]
    float Pr[2];
    #pragma unroll
    for (int qt = 0; qt < 2; qt++) {
        int qrow = qbase + qt * 16 + l15;
        Pr[qt] = qtab[(size_t)bh * NSEQ + qrow];
        #pragma unroll
        for (int ks = 0; ks < 2; ks++)
            qf[qt][ks] = *(const s16x8*)(Q + ((size_t)bh * NSEQ + qrow) * DH
                                         + ks * 32 + quad * 8);
    }

    // bpermute source-lane byte indices
    const int idx0 = ((quad & 1) * 32 + l15) * 4;
    const int idx2 = idx0 + 64;
    const bool selhi = quad >= 2;

    const f32x4 fz = {0.f, 0.f, 0.f, 0.f};
    f32x4 oacc[2][4];               // [qt][d-tile], O^T C-layout (col=q, row=d)
    f32x4 lsum[2];
    #pragma unroll
    for (int qt = 0; qt < 2; qt++) {
        lsum[qt] = fz;
        #pragma unroll
        for (int ni = 0; ni < 4; ni++) oacc[qt][ni] = fz;
    }

    s16x8 ones;
    #pragma unroll
    for (int j = 0; j < 8; j++) ones[j] = (short)0x3F80;  // bf16 1.0

    const float* ktb = ktab + (size_t)bh * NSEQ;
    const int jq = g * (NSEQ / 4);   // this group's 512-j range

    // stage one 32-j K/V tile pair: 256 chunks each, 1 load16/thread each
    auto stage = [&](int j0, char* lK, char* lV) {
        int linear = gt;              // 0..255
        {   // K tile: 32 rows x 8 chunks, swz8
            int row = linear >> 3, sc = linear & 7, gc = sc ^ (row & 7);
            load16_to_lds(K + ((size_t)bh * NSEQ + j0 + row) * DH + gc * 8,
                          lK + linear * 16);
        }
        {   // Vt tile: 64 d-rows x 4 chunks (32 j), swz (d>>1)&3
            int d = linear >> 2, sc = linear & 3, gc = sc ^ ((d >> 1) & 3);
            load16_to_lds(Vt + ((size_t)bh * DH + d) * NSEQ + j0 + gc * 8,
                          lV + linear * 16);
        }
    };

    // compute one 32-j tile from (lK, lV) at global j-offset j0
    auto compute = [&](const char* lK, const char* lV, int j0) {
        // S' = K Q'^T: two 16-j tiles x two q-tiles (kf shared across qt)
        f32x4 s2[2][2];                       // [qt][t]
        #pragma unroll
        for (int qt = 0; qt < 2; qt++)
            #pragma unroll
            for (int t = 0; t < 2; t++) s2[qt][t] = fz;
        __builtin_amdgcn_s_setprio(1);
        #pragma unroll
        for (int t = 0; t < 2; t++) {
            int row = t * 16 + l15;
            #pragma unroll
            for (int ks = 0; ks < 2; ks++) {
                s16x8 kf = *(const s16x8*)(lK + row * 128
                             + (((ks * 4 + quad) ^ (row & 7)) * 16));
                #pragma unroll
                for (int qt = 0; qt < 2; qt++)
                    s2[qt][t] = __builtin_amdgcn_mfma_f32_16x16x32_bf16(
                        kf, qf[qt][ks], s2[qt][t], 0, 0, 0);
            }
        }
        __builtin_amdgcn_s_setprio(0);
        // transform + pack: z = Pr*Pc - s2 (R factors folded into Q,K)
        uint32_t d0[2][2], d1[2][2];          // [qt][t]
        #pragma unroll
        for (int t = 0; t < 2; t++) {
            float4 pc = *(const float4*)(ktb + j0 + t * 16 + quad * 4);
            #pragma unroll
            for (int qt = 0; qt < 2; qt++) {
                float z0 = fmaf(Pr[qt], pc.x, -s2[qt][t][0]);
                float z1 = fmaf(Pr[qt], pc.y, -s2[qt][t][1]);
                float z2 = fmaf(Pr[qt], pc.z, -s2[qt][t][2]);
                float z3 = fmaf(Pr[qt], pc.w, -s2[qt][t][3]);
                z0 = fmaxf(z0, 1.0f); z1 = fmaxf(z1, 1.0f);
                z2 = fmaxf(z2, 1.0f); z3 = fmaxf(z3, 1.0f);
                float p0 = z0 - __builtin_amdgcn_sqrtf(fmaf(z0, z0, -1.0f));
                float p1 = z1 - __builtin_amdgcn_sqrtf(fmaf(z1, z1, -1.0f));
                float p2 = z2 - __builtin_amdgcn_sqrtf(fmaf(z2, z2, -1.0f));
                float p3 = z3 - __builtin_amdgcn_sqrtf(fmaf(z3, z3, -1.0f));
                d0[qt][t] = cvtpk(p0, p1);
                d1[qt][t] = cvtpk(p2, p3);
            }
        }
        // build P' B-fragments via cross-lane pulls
        s16x8 pf[2];
        #pragma unroll
        for (int qt = 0; qt < 2; qt++) {
            int a0 = __builtin_amdgcn_ds_bpermute(idx0, (int)d0[qt][0]);
            int b0 = __builtin_amdgcn_ds_bpermute(idx0, (int)d0[qt][1]);
            int a1 = __builtin_amdgcn_ds_bpermute(idx0, (int)d1[qt][0]);
            int b1 = __builtin_amdgcn_ds_bpermute(idx0, (int)d1[qt][1]);
            int a2 = __builtin_amdgcn_ds_bpermute(idx2, (int)d0[qt][0]);
            int b2 = __builtin_amdgcn_ds_bpermute(idx2, (int)d0[qt][1]);
            int a3 = __builtin_amdgcn_ds_bpermute(idx2, (int)d1[qt][0]);
            int b3 = __builtin_amdgcn_ds_bpermute(idx2, (int)d1[qt][1]);
            union { int i[4]; s16x8 v; } pu;
            pu.i[0] = selhi ? b0 : a0;
            pu.i[1] = selhi ? b1 : a1;
            pu.i[2] = selhi ? b2 : a2;
            pu.i[3] = selhi ? b3 : a3;
            pf[qt] = pu.v;
        }

        // O^T += Vt-tile * P' (vf shared across qt) ; lsum += ones * P'
        __builtin_amdgcn_s_setprio(1);
        #pragma unroll
        for (int ni = 0; ni < 4; ni++) {
            int d = ni * 16 + l15;
            s16x8 vf = *(const s16x8*)(lV + d * 64
                         + ((quad ^ ((d >> 1) & 3)) * 16));
            #pragma unroll
            for (int qt = 0; qt < 2; qt++)
                oacc[qt][ni] = __builtin_amdgcn_mfma_f32_16x16x32_bf16(
                    vf, pf[qt], oacc[qt][ni], 0, 0, 0);
        }
        #pragma unroll
        for (int qt = 0; qt < 2; qt++)
            lsum[qt] = __builtin_amdgcn_mfma_f32_16x16x32_bf16(
                ones, pf[qt], lsum[qt], 0, 0, 0);
        __builtin_amdgcn_s_setprio(0);
    };

    // prologue: stage tile 0 into buf0
    stage(jq, bK0, bV0);
    __syncthreads();

    // 8 outer iterations x 2 tiles (buf0, buf1) = 16 x 32-j tiles (512 j)
    for (int jj = 0; jj < NSEQ / 4; jj += 64) {
        stage(jq + jj + 32, bK1, bV1);
        compute(bK0, bV0, jq + jj);
        __syncthreads();
        if (jj + 64 < NSEQ / 4)
            stage(jq + jj + 64, bK0, bV0);
        compute(bK1, bV1, jq + jj + 32);
        __syncthreads();
    }

    // ---- in-block combine: groups 1-3 -> LDS regions, group 0 adds+stores.
    // Per qt pass: 3 x (64 q x 68 fp32) = 52224B + 3x64 lsum = 52992B.
    const int b = bh >> 4, h = bh & 15;
    float* lxf = (float*)(smem + 52224);         // [3][64] fp32
    #pragma unroll
    for (int qt = 0; qt < 2; qt++) {
        __syncthreads();
        if (g >= 1) {
            float* oxf = (float*)(smem + (g - 1) * 17408);  // [64 q][68] fp32
            int qr = wq_ * 16 + l15;
            #pragma unroll
            for (int ni = 0; ni < 4; ni++)
                *(f32x4*)(oxf + qr * 68 + ni * 16 + quad * 4) = oacc[qt][ni];
            if (quad == 0) lxf[(g - 1) * 64 + qr] = lsum[qt][0];
        }
        __syncthreads();
        if (g == 0) {
            int qr = wq_ * 16 + l15;
            float rls = 1.0f / (lsum[qt][0] + lxf[qr] + lxf[64 + qr] + lxf[128 + qr]);
            size_t obase = ((size_t)b * NSEQ + qbase + qt * 16 + l15) * DMODEL
                           + h * DH + quad * 4;
            #pragma unroll
            for (int ni = 0; ni < 4; ni++) {
                int off = qr * 68 + ni * 16 + quad * 4;
                f32x4 o = oacc[qt][ni];
                o += *(const f32x4*)((float*)smem + off);
                o += *(const f32x4*)((float*)(smem + 17408) + off);
                o += *(const f32x4*)((float*)(smem + 34816) + off);
                uint2 st;
                st.x = pk2(o[0] * rls, o[1] * rls);
                st.y = pk2(o[2] * rls, o[3] * rls);
                *(uint2*)(Attw + obase + ni * 16) = st;
            }
        }
    }
}

// ---------------------------------------------------------------------------
extern "C" void kernel_launch(void* const* d_in, const int* in_sizes, int n_in,
                              void* d_out, int out_size, void* d_ws, size_t ws_size,
                              hipStream_t stream)
{
    const float* x  = (const float*)d_in[0];
    const float* wq = (const float*)d_in[1];
    const float* wk = (const float*)d_in[2];
    const float* wv = (const float*)d_in[3];
    const float* wo = (const float*)d_in[4];
    float* out = (float*)d_out;

    const size_t QSZ = (size_t)BH * NSEQ * DH;   // 4,194,304 elements
    const size_t WSZ = (size_t)DMODEL * DMODEL;  // 1,048,576 elements
    u16* xb   = (u16*)d_ws;           // 4M elem; reused as Attw after attn
    u16* wqb  = xb  + QSZ;
    u16* wkb  = wqb + WSZ;
    u16* wvb  = wkb + WSZ;
    u16* wob  = wvb + WSZ;
    u16* Qw   = wob + WSZ;
    u16* Kw   = Qw + QSZ;
    u16* Vtw  = Kw + QSZ;             // V written pre-transposed by gemm
    float* qtab = (float*)(Vtw + QSZ);
    float* ktab = qtab + (size_t)BH * NSEQ;
    u16*   Attw = xb;                 // overlay: x bf16 dead after QKV

    // 0. fp32 -> bf16 conversions
    cvt_kernel<<<dim3(512, 1, 8), 256, 0, stream>>>(x, wq, wk, wv, wo,
                                                    xb, wqb, wkb, wvb, wob);
    // 1. Q/K/V projections; Q,K pre-scaled by R; V pre-transposed; P tables
    gemm_bt<<<dim3(8, 32, 3), 256, 0, stream>>>(xb, wqb, wkb, wvb, Qw, Kw, Vtw,
                                                qtab, ktab);
    // 2. attention (128-q blocks, in-block 4-way kv-split, 32-j dbuf tiles)
    attn_kernel<<<dim3(NSEQ / 128, BH), 1024, 0, stream>>>(Qw, Kw, Vtw, qtab, ktab,
                                                           Attw);
    // 3. output projection -> d_out (fp32), 64-row tiles, double-buffered
    gemm_m64<<<dim3(8, 64), 256, 0, stream>>>(Attw, wob, out);
}

// Round 7
// 180.519 us; speedup vs baseline: 1.1060x; 1.1060x over previous
//
#include <hip/hip_runtime.h>
#include <hip/hip_bf16.h>
#include <stdint.h>

#define NSEQ   2048
#define DMODEL 1024
#define NH     16
#define DH     64
#define BATCH  2
#define BH     (BATCH*NH)           // 32
#define MROWS  (BATCH*NSEQ)         // 4096

typedef unsigned short u16;
typedef __attribute__((ext_vector_type(8))) short s16x8;
typedef __attribute__((ext_vector_type(4))) float f32x4;

__device__ __forceinline__ void load16_to_lds(const void* g, void* l) {
    __builtin_amdgcn_global_load_lds(
        (const __attribute__((address_space(1))) void*)g,
        (__attribute__((address_space(3))) void*)l,
        16, 0, 0);
}

__device__ __forceinline__ float bf2f(u16 u) {
    union { uint32_t i; float f; } x; x.i = ((uint32_t)u) << 16; return x.f;
}
__device__ __forceinline__ u16 f2bf(float f) {
    union { float f; uint32_t i; } x; x.f = f;
    uint32_t r = x.i + 0x7FFFu + ((x.i >> 16) & 1u);  // RNE
    return (u16)(r >> 16);
}
// pack two fp32 -> bf16 pair (lo in low16, hi in high16)
__device__ __forceinline__ uint32_t pk2(float lo, float hi) {
    union { float f; uint32_t i; } a, b; a.f = lo; b.f = hi;
    return __builtin_amdgcn_perm(b.i + 0x7FFFu, a.i + 0x7FFFu, 0x07060302u);
}
// single-instruction pack (HW RNE): dst.lo16 = bf16(lo), dst.hi16 = bf16(hi)
__device__ __forceinline__ uint32_t cvtpk(float lo, float hi) {
    uint32_t r;
    asm("v_cvt_pk_bf16_f32 %0, %1, %2" : "=v"(r) : "v"(lo), "v"(hi));
    return r;
}

// ---------------------------------------------------------------------------
// fp32 -> bf16 conversion. grid (512,1,8): z<4 -> quarter-slices of x (4M),
// z=4..7 -> wq/wk/wv/wo (1M each).  Packs via v_cvt_pk_bf16_f32 (HW RNE).
// ---------------------------------------------------------------------------
__global__ void cvt_kernel(
    const float* __restrict__ x,
    const float* __restrict__ wq, const float* __restrict__ wk,
    const float* __restrict__ wv, const float* __restrict__ wo,
    u16* __restrict__ xb,
    u16* __restrict__ wqb, u16* __restrict__ wkb,
    u16* __restrict__ wvb, u16* __restrict__ wob)
{
    int z = blockIdx.z;
    const float* s = (z < 4) ? x  : (z == 4 ? wq  : z == 5 ? wk  : z == 6 ? wv  : wo);
    u16*         d = (z < 4) ? xb : (z == 4 ? wqb : z == 5 ? wkb : z == 6 ? wvb : wob);
    size_t off = (z < 4) ? ((size_t)z << 20) : 0;
    size_t i = off + (size_t)blockIdx.x * 2048 + (size_t)threadIdx.x * 8;
    float4 a = *(const float4*)(s + i);
    float4 b = *(const float4*)(s + i + 4);
    uint4 st;
    st.x = cvtpk(a.x, a.y);
    st.y = cvtpk(a.z, a.w);
    st.z = cvtpk(b.x, b.y);
    st.w = cvtpk(b.z, b.w);
    *(uint4*)(d + i) = st;
}

// ---------------------------------------------------------------------------
// QKV GEMM: C = A @ W^T. 128x128 tile, BK=64, 256 threads, 2 blocks/CU.
// XOR chunk swizzle: chunk c of row r stored at c ^ (r&7).
// z<2 : bf16 scatter -> [B,H,N,DH], rows PRE-SCALED by R = 2/(1-||v||^2)
//       + P factor table (float).
// z==2: bf16 transposed scatter -> [B,H,DH,N]  (V -> Vt, fused)
// ---------------------------------------------------------------------------
__global__ __launch_bounds__(256, 2) void gemm_bt(
    const u16* __restrict__ A,
    const u16* __restrict__ W0, const u16* __restrict__ W1, const u16* __restrict__ W2,
    void* __restrict__ C0, void* __restrict__ C1, void* __restrict__ C2,
    float* __restrict__ qtab, float* __restrict__ ktab)
{
    __shared__ __align__(16) char smem[32768];
    char* ldsA = smem;            // 16KB: 128 rows x 8 chunks x 16B
    char* ldsW = smem + 16384;

    const u16* W = (blockIdx.z == 0) ? W0 : (blockIdx.z == 1 ? W1 : W2);
    void*      C = (blockIdx.z == 0) ? C0 : (blockIdx.z == 1 ? C1 : C2);

    const int tid  = threadIdx.x;
    const int lane = tid & 63;
    const int w    = tid >> 6;
    const int quad = lane >> 4;
    const int l15  = lane & 15;
    const int m0   = blockIdx.y * 128;
    const int n0   = blockIdx.x * 128;
    const int wr   = (w >> 1) * 64;
    const int wc   = (w & 1) * 64;

    f32x4 acc[4][4];
    const f32x4 fz = {0.f, 0.f, 0.f, 0.f};
    #pragma unroll
    for (int i = 0; i < 4; i++)
        #pragma unroll
        for (int j = 0; j < 4; j++) acc[i][j] = fz;

    for (int k0 = 0; k0 < DMODEL; k0 += 64) {
        __syncthreads();
        #pragma unroll
        for (int i = 0; i < 4; i++) {
            int linear = tid + i * 256;          // 0..1023
            int row = linear >> 3;
            int sc  = linear & 7;
            int gc  = sc ^ (row & 7);
            load16_to_lds(A + (size_t)(m0 + row) * DMODEL + k0 + gc * 8, ldsA + linear * 16);
            load16_to_lds(W + (size_t)(n0 + row) * DMODEL + k0 + gc * 8, ldsW + linear * 16);
        }
        __syncthreads();
        #pragma unroll
        for (int ks = 0; ks < 2; ks++) {
            s16x8 af[4], bf[4];
            #pragma unroll
            for (int mi = 0; mi < 4; mi++) {
                int row = wr + mi * 16 + l15;
                int ch  = (ks * 4 + quad) ^ (row & 7);
                af[mi] = *(const s16x8*)(ldsA + row * 128 + ch * 16);
            }
            #pragma unroll
            for (int ni = 0; ni < 4; ni++) {
                int row = wc + ni * 16 + l15;
                int ch  = (ks * 4 + quad) ^ (row & 7);
                bf[ni] = *(const s16x8*)(ldsW + row * 128 + ch * 16);
            }
            #pragma unroll
            for (int mi = 0; mi < 4; mi++)
                #pragma unroll
                for (int ni = 0; ni < 4; ni++)
                    acc[mi][ni] = __builtin_amdgcn_mfma_f32_16x16x32_bf16(
                        af[mi], bf[ni], acc[mi][ni], 0, 0, 0);
        }
    }

    if (blockIdx.z < 2) {
        // Q / K: row-norm first, then store rows pre-scaled by R; table = P.
        float* tab = (blockIdx.z == 0) ? qtab : ktab;
        int h = (n0 + wc) >> 6;      // wave's 64-col span = one head
        #pragma unroll
        for (int mi = 0; mi < 4; mi++)
            #pragma unroll
            for (int r = 0; r < 4; r++) {
                int m = m0 + wr + mi * 16 + quad * 4 + r;
                int b = m >> 11, n = m & (NSEQ - 1);
                float ss = 0.f;
                #pragma unroll
                for (int ni = 0; ni < 4; ni++) {
                    float v = acc[mi][ni][r];
                    ss = fmaf(v, v, ss);
                }
                // butterfly over the 16-lane group -> full ||row||^2 in all
                ss += __shfl_xor(ss, 1);
                ss += __shfl_xor(ss, 2);
                ss += __shfl_xor(ss, 4);
                ss += __shfl_xor(ss, 8);
                float rr = 1.0f / (1.0f - ss);
                float Rr = 2.0f * rr;
                #pragma unroll
                for (int ni = 0; ni < 4; ni++) {
                    int o = n0 + wc + ni * 16 + l15;
                    int d = o & 63;
                    ((u16*)C)[(((size_t)(b * NH + h)) * NSEQ + n) * DH + d] =
                        f2bf(acc[mi][ni][r] * Rr);
                }
                if (l15 == 0)
                    tab[(size_t)(b * NH + h) * NSEQ + n] = (1.0f + ss) * rr;
            }
    } else {
        // V transposed: r=0..3 are consecutive n -> packed 8B stores
        #pragma unroll
        for (int mi = 0; mi < 4; mi++) {
            int mrow = m0 + wr + mi * 16 + quad * 4;
            int b = mrow >> 11, n = mrow & (NSEQ - 1);
            #pragma unroll
            for (int ni = 0; ni < 4; ni++) {
                int o = n0 + wc + ni * 16 + l15;
                int h = o >> 6, d = o & 63;
                uint2 st;
                st.x = pk2(acc[mi][ni][0], acc[mi][ni][1]);
                st.y = pk2(acc[mi][ni][2], acc[mi][ni][3]);
                *(uint2*)((u16*)C + (((size_t)(b * NH + h)) * DH + d) * NSEQ + n) = st;
            }
        }
    }
}

// ---------------------------------------------------------------------------
// Output-projection GEMM: C(fp32) = A @ W^T with 64(M)x128(N) tiles.
// 512 blocks -> 2 blocks/CU.  256 threads; wave = 32 rows x 64 cols.
// Double-buffered staging (r5).  LDS 48KB.
// ---------------------------------------------------------------------------
__global__ __launch_bounds__(256, 2) void gemm_m64(
    const u16* __restrict__ A, const u16* __restrict__ W, float* __restrict__ C)
{
    __shared__ __align__(16) char smem[49152];
    char* A0 = smem;
    char* W0p = smem + 8192;
    char* A1 = smem + 24576;
    char* W1p = smem + 32768;

    const int tid  = threadIdx.x;
    const int lane = tid & 63;
    const int w    = tid >> 6;
    const int quad = lane >> 4;
    const int l15  = lane & 15;
    const int m0   = blockIdx.y * 64;
    const int n0   = blockIdx.x * 128;
    const int wr   = (w >> 1) * 32;
    const int wc   = (w & 1) * 64;

    f32x4 acc[2][4];
    const f32x4 fz = {0.f, 0.f, 0.f, 0.f};
    #pragma unroll
    for (int i = 0; i < 2; i++)
        #pragma unroll
        for (int j = 0; j < 4; j++) acc[i][j] = fz;

    auto stage = [&](int k0, char* lA, char* lW) {
        #pragma unroll
        for (int i = 0; i < 2; i++) {           // A: 512 chunks
            int linear = tid + i * 256;
            int row = linear >> 3, sc = linear & 7, gc = sc ^ (row & 7);
            load16_to_lds(A + (size_t)(m0 + row) * DMODEL + k0 + gc * 8,
                          lA + linear * 16);
        }
        #pragma unroll
        for (int i = 0; i < 4; i++) {           // W: 1024 chunks
            int linear = tid + i * 256;
            int row = linear >> 3, sc = linear & 7, gc = sc ^ (row & 7);
            load16_to_lds(W + (size_t)(n0 + row) * DMODEL + k0 + gc * 8,
                          lW + linear * 16);
        }
    };

    auto compute = [&](const char* lA, const char* lW) {
        #pragma unroll
        for (int ks = 0; ks < 2; ks++) {
            s16x8 af[2], bf[4];
            #pragma unroll
            for (int mi = 0; mi < 2; mi++) {
                int row = wr + mi * 16 + l15;
                int ch  = (ks * 4 + quad) ^ (row & 7);
                af[mi] = *(const s16x8*)(lA + row * 128 + ch * 16);
            }
            #pragma unroll
            for (int ni = 0; ni < 4; ni++) {
                int row = wc + ni * 16 + l15;
                int ch  = (ks * 4 + quad) ^ (row & 7);
                bf[ni] = *(const s16x8*)(lW + row * 128 + ch * 16);
            }
            #pragma unroll
            for (int mi = 0; mi < 2; mi++)
                #pragma unroll
                for (int ni = 0; ni < 4; ni++)
                    acc[mi][ni] = __builtin_amdgcn_mfma_f32_16x16x32_bf16(
                        af[mi], bf[ni], acc[mi][ni], 0, 0, 0);
        }
    };

    stage(0, A0, W0p);
    __syncthreads();
    for (int k0 = 0; k0 < DMODEL; k0 += 128) {
        stage(k0 + 64, A1, W1p);
        compute(A0, W0p);
        __syncthreads();
        if (k0 + 128 < DMODEL)
            stage(k0 + 128, A0, W0p);
        compute(A1, W1p);
        __syncthreads();
    }

    #pragma unroll
    for (int mi = 0; mi < 2; mi++)
        #pragma unroll
        for (int r = 0; r < 4; r++) {
            int m = m0 + wr + mi * 16 + quad * 4 + r;
            #pragma unroll
            for (int ni = 0; ni < 4; ni++) {
                int o = n0 + wc + ni * 16 + l15;
                C[(size_t)m * DMODEL + o] = acc[mi][ni][r];
            }
        }
}

// ---------------------------------------------------------------------------
// Attention v8 = r5 structure (proven 68.4us: 512 thr, 2-way in-block
// kv-split, 64-j double-buffered tiles, 64KB LDS, single-pass epilogue)
//   + XCD-AWARE BLOCK REMAP (T1): default linear dispatch round-robins the
//     16 q-blocks of one bh across all 8 XCDs -> every XCD re-fetches that
//     bh's K/V (512KB) through L3 (FETCH 71MB vs ~17MB ideal).  Remap the
//     linear id L so bh == L (mod 8): all 16 q-blocks of a bh land on ONE
//     XCD; each XCD serves 4 bh = 2MB K/V, fits 4MB L2.  Bijective:
//     u=L>>3, r=L&7; bh=r+8*(u>>4); qb=u&15.  Correctness-neutral.
// DO NOT REVISIT (measured): occupancy pushes -- r1 1024thr cap-64 spill;
// r3 64q blocks 104us; r6 1024thr/32j-tiles 76us, occ counter 41 only.
// launch_bounds (512,4): do NOT tighten.  Scalar transform (pk-f32 spills).
// ---------------------------------------------------------------------------
__global__ __launch_bounds__(512, 4) void attn_kernel(
    const u16* __restrict__ Q,      // [BH][NSEQ][DH]  (pre-scaled by Rq)
    const u16* __restrict__ K,      // [BH][NSEQ][DH]  (pre-scaled by Rk)
    const u16* __restrict__ Vt,     // [BH][DH][NSEQ]
    const float* __restrict__ qtab, // P_q per row
    const float* __restrict__ ktab, // P_k per row
    u16* __restrict__ Attw)         // [B][NSEQ][DMODEL] bf16
{
    __shared__ __align__(16) char smem[65536];

    const int tid  = threadIdx.x;
    const int lane = tid & 63;
    const int w    = tid >> 6;       // 0..7
    const int g    = w >> 2;         // j-half group
    const int wq_  = w & 3;
    const int quad = lane >> 4;
    const int l15  = lane & 15;

    // T1 XCD remap: linear id L -> (bh, qblock) with bh == L (mod 8)
    const int L    = blockIdx.y * 16 + blockIdx.x;   // gridDim.x == 16
    const int u_   = L >> 3;
    const int bh   = (L & 7) + 8 * (u_ >> 4);
    const int i0   = (u_ & 15) * 128;

    const int qbase = i0 + wq_ * 32;
    const int gt   = tid & 255;      // tid within group

    // double-buffered tiles: buf0 = [0,32K), buf1 = [32K,64K)
    char* bK0 = smem + g * 8192;             // 64 j-rows x 128B, swz8
    char* bV0 = smem + 16384 + g * 8192;     // 64 d-rows x 128B (64 j), swz8
    char* bK1 = bK0 + 32768;
    char* bV1 = bV0 + 32768;

    // Q fragments (B-operand layout) -- already R-scaled at the source
    s16x8 qf[2][2];                 // [qt][ks]
    float Pr[2];
    #pragma unroll
    for (int qt = 0; qt < 2; qt++) {
        int qrow = qbase + qt * 16 + l15;
        Pr[qt] = qtab[(size_t)bh * NSEQ + qrow];
        #pragma unroll
        for (int ks = 0; ks < 2; ks++)
            qf[qt][ks] = *(const s16x8*)(Q + ((size_t)bh * NSEQ + qrow) * DH
                                         + ks * 32 + quad * 8);
    }

    // bpermute source-lane byte indices
    const int idx0 = ((quad & 1) * 32 + l15) * 4;
    const int idx2 = idx0 + 64;
    const bool selhi = quad >= 2;

    const f32x4 fz = {0.f, 0.f, 0.f, 0.f};
    f32x4 oacc[2][4];               // [qt][d-tile], O^T C-layout (col=q, row=d)
    f32x4 lsum[2];
    #pragma unroll
    for (int qt = 0; qt < 2; qt++) {
        lsum[qt] = fz;
        #pragma unroll
        for (int ni = 0; ni < 4; ni++) oacc[qt][ni] = fz;
    }

    s16x8 ones;
    #pragma unroll
    for (int j = 0; j < 8; j++) ones[j] = (short)0x3F80;  // bf16 1.0

    const float* ktb = ktab + (size_t)bh * NSEQ;
    const int jhalf = g * (NSEQ / 2);

    // stage one 64-j K/V tile pair into (lK, lV); both use row=linear>>3, swz8
    auto stage = [&](int j0, char* lK, char* lV) {
        #pragma unroll
        for (int i = 0; i < 2; i++) {
            int linear = gt + i * 256;    // 0..511 within group
            int row = linear >> 3, sc = linear & 7, gc = sc ^ (row & 7);
            load16_to_lds(K + ((size_t)bh * NSEQ + j0 + row) * DH + gc * 8,
                          lK + linear * 16);
            load16_to_lds(Vt + ((size_t)bh * DH + row) * NSEQ + j0 + gc * 8,
                          lV + linear * 16);
        }
    };

    // compute one 64-j tile from (lK, lV) at global j-offset j0
    auto compute = [&](const char* lK, const char* lV, int j0) {
        #pragma unroll
        for (int cb = 0; cb < 2; cb++) {          // 32 j per chunk
            // S' = K Q'^T: two 16-j tiles x two q-tiles (kf shared across qt)
            f32x4 s2[2][2];                       // [qt][t]
            #pragma unroll
            for (int qt = 0; qt < 2; qt++)
                #pragma unroll
                for (int t = 0; t < 2; t++) s2[qt][t] = fz;
            __builtin_amdgcn_s_setprio(1);
            #pragma unroll
            for (int t = 0; t < 2; t++) {
                int row = (cb * 2 + t) * 16 + l15;
                #pragma unroll
                for (int ks = 0; ks < 2; ks++) {
                    s16x8 kf = *(const s16x8*)(lK + row * 128
                                 + (((ks * 4 + quad) ^ (row & 7)) * 16));
                    #pragma unroll
                    for (int qt = 0; qt < 2; qt++)
                        s2[qt][t] = __builtin_amdgcn_mfma_f32_16x16x32_bf16(
                            kf, qf[qt][ks], s2[qt][t], 0, 0, 0);
                }
            }
            __builtin_amdgcn_s_setprio(0);
            // transform + pack: z = Pr*Pc - s2 (R factors folded into Q,K)
            uint32_t d0[2][2], d1[2][2];          // [qt][t]
            #pragma unroll
            for (int t = 0; t < 2; t++) {
                float4 pc = *(const float4*)(ktb + j0 + (cb * 2 + t) * 16 + quad * 4);
                #pragma unroll
                for (int qt = 0; qt < 2; qt++) {
                    float z0 = fmaf(Pr[qt], pc.x, -s2[qt][t][0]);
                    float z1 = fmaf(Pr[qt], pc.y, -s2[qt][t][1]);
                    float z2 = fmaf(Pr[qt], pc.z, -s2[qt][t][2]);
                    float z3 = fmaf(Pr[qt], pc.w, -s2[qt][t][3]);
                    z0 = fmaxf(z0, 1.0f); z1 = fmaxf(z1, 1.0f);
                    z2 = fmaxf(z2, 1.0f); z3 = fmaxf(z3, 1.0f);
                    float p0 = z0 - __builtin_amdgcn_sqrtf(fmaf(z0, z0, -1.0f));
                    float p1 = z1 - __builtin_amdgcn_sqrtf(fmaf(z1, z1, -1.0f));
                    float p2 = z2 - __builtin_amdgcn_sqrtf(fmaf(z2, z2, -1.0f));
                    float p3 = z3 - __builtin_amdgcn_sqrtf(fmaf(z3, z3, -1.0f));
                    d0[qt][t] = cvtpk(p0, p1);
                    d1[qt][t] = cvtpk(p2, p3);
                }
            }
            // build P' B-fragments via cross-lane pulls
            s16x8 pf[2];
            #pragma unroll
            for (int qt = 0; qt < 2; qt++) {
                int a0 = __builtin_amdgcn_ds_bpermute(idx0, (int)d0[qt][0]);
                int b0 = __builtin_amdgcn_ds_bpermute(idx0, (int)d0[qt][1]);
                int a1 = __builtin_amdgcn_ds_bpermute(idx0, (int)d1[qt][0]);
                int b1 = __builtin_amdgcn_ds_bpermute(idx0, (int)d1[qt][1]);
                int a2 = __builtin_amdgcn_ds_bpermute(idx2, (int)d0[qt][0]);
                int b2 = __builtin_amdgcn_ds_bpermute(idx2, (int)d0[qt][1]);
                int a3 = __builtin_amdgcn_ds_bpermute(idx2, (int)d1[qt][0]);
                int b3 = __builtin_amdgcn_ds_bpermute(idx2, (int)d1[qt][1]);
                union { int i[4]; s16x8 v; } pu;
                pu.i[0] = selhi ? b0 : a0;
                pu.i[1] = selhi ? b1 : a1;
                pu.i[2] = selhi ? b2 : a2;
                pu.i[3] = selhi ? b3 : a3;
                pf[qt] = pu.v;
            }

            // O^T += Vt-tile * P' (vf shared across qt) ; lsum += ones * P'
            __builtin_amdgcn_s_setprio(1);
            #pragma unroll
            for (int ni = 0; ni < 4; ni++) {
                int d = ni * 16 + l15;
                s16x8 vf = *(const s16x8*)(lV + d * 128
                             + (((cb * 4 + quad) ^ (d & 7)) * 16));
                #pragma unroll
                for (int qt = 0; qt < 2; qt++)
                    oacc[qt][ni] = __builtin_amdgcn_mfma_f32_16x16x32_bf16(
                        vf, pf[qt], oacc[qt][ni], 0, 0, 0);
            }
            #pragma unroll
            for (int qt = 0; qt < 2; qt++)
                lsum[qt] = __builtin_amdgcn_mfma_f32_16x16x32_bf16(
                    ones, pf[qt], lsum[qt], 0, 0, 0);
            __builtin_amdgcn_s_setprio(0);
        }
    };

    // prologue: stage tile 0 into buf0
    stage(jhalf, bK0, bV0);
    __syncthreads();

    // 8 outer iterations x 2 tiles (A: buf0, B: buf1) = 16 x 64-j tiles
    for (int jj = 0; jj < NSEQ / 2; jj += 128) {
        stage(jhalf + jj + 64, bK1, bV1);
        compute(bK0, bV0, jhalf + jj);
        __syncthreads();
        if (jj + 128 < NSEQ / 2)
            stage(jhalf + jj + 128, bK0, bV0);
        compute(bK1, bV1, jhalf + jj + 64);
        __syncthreads();
    }

    // ---- in-block combine: group 1 -> LDS, group 0 adds + stores ----
    // single pass: [128 q][68] fp32 = 34816B + 512B lsum (fits 64KB)
    float* oxfer = (float*)smem;
    float* lxfer = (float*)(smem + 34816);
    if (g == 1) {
        #pragma unroll
        for (int qt = 0; qt < 2; qt++) {
            int ql = wq_ * 32 + qt * 16 + l15;
            #pragma unroll
            for (int ni = 0; ni < 4; ni++)
                *(f32x4*)(oxfer + ql * 68 + ni * 16 + quad * 4) = oacc[qt][ni];
            if (quad == 0) lxfer[ql] = lsum[qt][0];
        }
    }
    __syncthreads();
    if (g == 0) {
        const int b = bh >> 4, h = bh & 15;
        #pragma unroll
        for (int qt = 0; qt < 2; qt++) {
            int ql = wq_ * 32 + qt * 16 + l15;
            float rls = 1.0f / (lsum[qt][0] + lxfer[ql]);
            size_t obase = ((size_t)b * NSEQ + qbase + qt * 16 + l15) * DMODEL
                           + h * DH + quad * 4;
            #pragma unroll
            for (int ni = 0; ni < 4; ni++) {
                f32x4 add = *(const f32x4*)(oxfer + ql * 68 + ni * 16 + quad * 4);
                f32x4 o = oacc[qt][ni] + add;
                uint2 st;
                st.x = pk2(o[0] * rls, o[1] * rls);
                st.y = pk2(o[2] * rls, o[3] * rls);
                *(uint2*)(Attw + obase + ni * 16) = st;
            }
        }
    }
}

// ---------------------------------------------------------------------------
extern "C" void kernel_launch(void* const* d_in, const int* in_sizes, int n_in,
                              void* d_out, int out_size, void* d_ws, size_t ws_size,
                              hipStream_t stream)
{
    const float* x  = (const float*)d_in[0];
    const float* wq = (const float*)d_in[1];
    const float* wk = (const float*)d_in[2];
    const float* wv = (const float*)d_in[3];
    const float* wo = (const float*)d_in[4];
    float* out = (float*)d_out;

    const size_t QSZ = (size_t)BH * NSEQ * DH;   // 4,194,304 elements
    const size_t WSZ = (size_t)DMODEL * DMODEL;  // 1,048,576 elements
    u16* xb   = (u16*)d_ws;           // 4M elem; reused as Attw after attn
    u16* wqb  = xb  + QSZ;
    u16* wkb  = wqb + WSZ;
    u16* wvb  = wkb + WSZ;
    u16* wob  = wvb + WSZ;
    u16* Qw   = wob + WSZ;
    u16* Kw   = Qw + QSZ;
    u16* Vtw  = Kw + QSZ;             // V written pre-transposed by gemm
    float* qtab = (float*)(Vtw + QSZ);
    float* ktab = qtab + (size_t)BH * NSEQ;
    u16*   Attw = xb;                 // overlay: x bf16 dead after QKV

    // 0. fp32 -> bf16 conversions
    cvt_kernel<<<dim3(512, 1, 8), 256, 0, stream>>>(x, wq, wk, wv, wo,
                                                    xb, wqb, wkb, wvb, wob);
    // 1. Q/K/V projections; Q,K pre-scaled by R; V pre-transposed; P tables
    gemm_bt<<<dim3(8, 32, 3), 256, 0, stream>>>(xb, wqb, wkb, wvb, Qw, Kw, Vtw,
                                                qtab, ktab);
    // 2. attention (r5 structure + XCD-aware block remap)
    attn_kernel<<<dim3(NSEQ / 128, BH), 512, 0, stream>>>(Qw, Kw, Vtw, qtab, ktab,
                                                          Attw);
    // 3. output projection -> d_out (fp32), 64-row tiles, double-buffered
    gemm_m64<<<dim3(8, 64), 256, 0, stream>>>(Attw, wob, out);
}